// Round 4
// baseline (832.051 us; speedup 1.0000x reference)
//
#include <hip/hip_runtime.h>
#include <cstdint>

#define N_NODES 100000
#define N_EDGES 3200000
#define N_GRAPHS 64
#define HDIM 256
#define F_IN 128

#define BUCKET_BITS 7
#define NPB 128                                 // nodes per bucket
#define N_BUCKETS ((N_NODES + NPB - 1) / NPB)   // 782
#define CHUNK 8192
#define NCHUNK ((N_EDGES + CHUNK - 1) / CHUNK)  // 391
#define NODE_PAD (N_BUCKETS * NPB)              // 100096 (bucket-aligned array size)

typedef __attribute__((ext_vector_type(8))) short bf16x8;
typedef __attribute__((ext_vector_type(4))) float f32x4;
typedef __attribute__((ext_vector_type(2))) float f32x2;
typedef __attribute__((ext_vector_type(4))) int i32x4;
typedef __attribute__((ext_vector_type(4))) unsigned int u32x4;

// fp8 slice row stride: (N+1) rows of 32B (row N is the zero row for CSR padding)
#define SIN ((size_t)(N_NODES + 1) * 32)
// bf16 slice-major A stride in ushort elements
#define ASE ((size_t)N_NODES * 32)

// ---------------- bf16 helpers ----------------
__device__ __forceinline__ unsigned short f2bf(float f) {
    unsigned int b = __float_as_uint(f);
    b = (b + 0x7FFFu + ((b >> 16) & 1u)) >> 16;
    return (unsigned short)b;
}
__device__ __forceinline__ float bf2f(unsigned short u) {
    return __uint_as_float((unsigned int)u << 16);
}

// ---------------- fp8 e4m3 helpers (HW cvt) ----------------
__device__ __forceinline__ unsigned int pack4_fp8(float a, float b, float c, float d) {
    int v = 0;
    v = __builtin_amdgcn_cvt_pk_fp8_f32(a, b, v, false);  // bytes 0,1
    v = __builtin_amdgcn_cvt_pk_fp8_f32(c, d, v, true);   // bytes 2,3
    return (unsigned int)v;
}
__device__ __forceinline__ unsigned char pack1_fp8(float a) {
    int v = __builtin_amdgcn_cvt_pk_fp8_f32(a, a, 0, false);
    return (unsigned char)(v & 0xFF);
}

// ---------------- utility ----------------
__global__ void zero_f(float* p, int n) {
    int i = blockIdx.x * blockDim.x + threadIdx.x;
    if (i < n) p[i] = 0.0f;
}

// zero the pad rows (index N_NODES) of the fp8 slice buffers
__global__ void zero_rows(unsigned int* xp, unsigned int* hp) {
    int t = threadIdx.x;
    if (t < 32)  // 4 slices x 8 dwords
        xp[(size_t)(t >> 3) * ((size_t)(N_NODES + 1) * 8) + (size_t)N_NODES * 8 + (t & 7)] = 0;
    if (t >= 32 && t < 96) {  // 8 slices x 8 dwords
        int u = t - 32;
        hp[(size_t)(u >> 3) * ((size_t)(N_NODES + 1) * 8) + (size_t)N_NODES * 8 + (u & 7)] = 0;
    }
}

// ---------------- atomic-free multisplit CSR build ----------------
__global__ __launch_bounds__(256) void block_count(const int* __restrict__ dst,
                                                   int* __restrict__ counts, int nE) {
    __shared__ int hist[N_BUCKETS];
    int blk = blockIdx.x, t = threadIdx.x;
    for (int i = t; i < N_BUCKETS; i += 256) hist[i] = 0;
    __syncthreads();
    int lo = blk * CHUNK;
    int hi = lo + CHUNK < nE ? lo + CHUNK : nE;
    for (int i = lo + t; i < hi; i += 256) atomicAdd(&hist[dst[i] >> BUCKET_BITS], 1);
    __syncthreads();
    for (int i = t; i < N_BUCKETS; i += 256) counts[blk * N_BUCKETS + i] = hist[i];
}

__global__ __launch_bounds__(256) void bucket_totals(const int* __restrict__ counts,
                                                     int* __restrict__ tot) {
    __shared__ int red[256];
    int b = blockIdx.x, t = threadIdx.x;
    int s = 0;
    for (int blk = t; blk < NCHUNK; blk += 256) s += counts[blk * N_BUCKETS + b];
    red[t] = s;
    __syncthreads();
    for (int o = 128; o > 0; o >>= 1) {
        if (t < o) red[t] += red[t + o];
        __syncthreads();
    }
    if (t == 0) tot[b] = red[0];
}

__global__ __launch_bounds__(1024) void scan_buckets(const int* __restrict__ tot,
                                                     int* __restrict__ base, int nb) {
    __shared__ int lds[1024];
    int t = threadIdx.x;
    int v = (t < nb) ? tot[t] : 0;
    lds[t] = v;
    __syncthreads();
    for (int off = 1; off < 1024; off <<= 1) {
        int a = (t >= off) ? lds[t - off] : 0;
        __syncthreads();
        lds[t] += a;
        __syncthreads();
    }
    int excl = lds[t] - v;
    if (t < nb) base[t] = excl;
    if (t == nb) base[t] = excl;
}

__global__ __launch_bounds__(512) void column_scan(const int* __restrict__ counts,
                                                   const int* __restrict__ base,
                                                   int* __restrict__ offs) {
    __shared__ int lds[512];
    int b = blockIdx.x, t = threadIdx.x;
    int v = (t < NCHUNK) ? counts[t * N_BUCKETS + b] : 0;
    lds[t] = v;
    __syncthreads();
    for (int off = 1; off < 512; off <<= 1) {
        int a = (t >= off) ? lds[t - off] : 0;
        __syncthreads();
        lds[t] += a;
        __syncthreads();
    }
    if (t < NCHUNK) offs[t * N_BUCKETS + b] = base[b] + lds[t] - v;
}

__global__ __launch_bounds__(256) void block_scatter(const int* __restrict__ src,
                                                     const int* __restrict__ dst,
                                                     const int* __restrict__ offs,
                                                     unsigned int* __restrict__ rec, int nE) {
    __shared__ int cur[N_BUCKETS];
    int blk = blockIdx.x, t = threadIdx.x;
    for (int i = t; i < N_BUCKETS; i += 256) cur[i] = offs[blk * N_BUCKETS + i];
    __syncthreads();
    int lo = blk * CHUNK;
    int hi = lo + CHUNK < nE ? lo + CHUNK : nE;
    for (int i = lo + t; i < hi; i += 256) {
        int d = dst[i];
        int b = d >> BUCKET_BITS;
        int pos = atomicAdd(&cur[b], 1);  // LDS atomic
        rec[pos] = (unsigned int)src[i] | ((unsigned int)(d & (NPB - 1)) << 17);
    }
}

// Phase A: per-node degree + dinv + per-bucket padded totals
__global__ __launch_bounds__(512) void bucket_csr_a(const unsigned int* __restrict__ rec,
                                                    const int* __restrict__ base,
                                                    int* __restrict__ deg,
                                                    float* __restrict__ dinv,
                                                    int* __restrict__ ptot, int n) {
    __shared__ int hist[NPB];
    __shared__ int red[NPB];
    int b = blockIdx.x;
    int lo = base[b], hi = base[b + 1];
    int t = threadIdx.x;
    if (t < NPB) hist[t] = 0;
    __syncthreads();
    for (int i = lo + t; i < hi; i += 512) atomicAdd(&hist[rec[i] >> 17], 1);
    __syncthreads();
    if (t < NPB) {
        int node = b * NPB + t;
        int dg = hist[t];  // nodes >= n never occur in rec -> dg == 0
        deg[node] = dg;
        dinv[node] = rsqrtf((float)dg + 1.0f);
        red[t] = (dg + 7) & ~7;
    }
    __syncthreads();
    for (int o = 64; o > 0; o >>= 1) {
        if (t < o) red[t] += red[t + o];
        __syncthreads();
    }
    if (t == 0) ptot[b] = red[0];
}

// Phase B: padded per-node segments; scatter edges; fill pad slots with zero-node (n)
__global__ __launch_bounds__(512) void bucket_csr_b(const unsigned int* __restrict__ rec,
                                                    const int* __restrict__ base,
                                                    const int* __restrict__ deg,
                                                    const int* __restrict__ pbase,
                                                    int* __restrict__ pbeg, int* __restrict__ pend,
                                                    int* __restrict__ cpad, int n) {
    __shared__ int sc[NPB];
    __shared__ int cur[NPB];
    int b = blockIdx.x;
    int lo = base[b], hi = base[b + 1];
    int t = threadIdx.x;
    int dg = 0, pdg = 0;
    if (t < NPB) {
        dg = deg[b * NPB + t];
        pdg = (dg + 7) & ~7;
        sc[t] = pdg;
    }
    __syncthreads();
    for (int off = 1; off < NPB; off <<= 1) {
        int a = (t < NPB && t >= off) ? sc[t - off] : 0;
        __syncthreads();
        if (t < NPB) sc[t] += a;
        __syncthreads();
    }
    int pos0 = 0;
    if (t < NPB) {
        pos0 = pbase[b] + sc[t] - pdg;
        int node = b * NPB + t;
        if (node < n) {
            pbeg[node] = pos0;
            pend[node] = pos0 + pdg;
        }
        cur[t] = pos0;
    }
    __syncthreads();
    for (int i = lo + t; i < hi; i += 512) {
        unsigned int r = rec[i];
        int pos = atomicAdd(&cur[r >> 17], 1);
        cpad[pos] = (int)(r & 0x1FFFFu);
    }
    // fill pad slots (disjoint from scattered region; no sync needed)
    if (t < NPB) {
        for (int p = pos0 + dg; p < pos0 + pdg; p++) cpad[p] = n;  // zero-node index
    }
}

// ---------------- x -> fp8 pre-scaled, SLICE-MAJOR: xp[slice][node][8 dwords] ----------------
__global__ void convert_x_pre(const float* __restrict__ x, const float* __restrict__ dinv,
                              unsigned int* __restrict__ xp, int n) {
    int tid = blockIdx.x * blockDim.x + threadIdx.x;  // over n*F_IN/4 dword groups
    if (tid >= n * (F_IN / 4)) return;
    int node = tid >> 5;  // F_IN/4 = 32 dwords per node
    int d = tid & 31;     // dword within node; slice = d>>3
    float di = dinv[node];
    float4 v = ((const float4*)x)[tid];
    xp[(size_t)(d >> 3) * ((size_t)(N_NODES + 1) * 8) + (size_t)node * 8 + (d & 7)] =
        pack4_fp8(v.x * di, v.y * di, v.z * di, v.w * di);
}

// ---------------- pack W[K][256] fp32 -> hi/lo bf16 in MFMA B-fragment order ----------------
__global__ void pack_w(const float* __restrict__ W, unsigned short* __restrict__ hi,
                       unsigned short* __restrict__ lo, int K) {
    int idx = blockIdx.x * blockDim.x + threadIdx.x;
    if (idx >= K * HDIM) return;
    int k = idx >> 8, c = idx & 255;
    float w = W[idx];
    unsigned short h = f2bf(w);
    float hf = __uint_as_float((unsigned int)h << 16);
    unsigned short l = f2bf(w - hf);
    int pos = ((k >> 5) * 16 + (c >> 4)) * 512 + ((((k >> 3) & 3) * 16) + (c & 15)) * 8 + (k & 7);
    hi[pos] = h;
    lo[pos] = l;
}

// ---------------- XCD-pinned feature-sliced aggregation, padded CSR, nt streams -------------
// Input h: fp8, slice-major [NS][N+1][32B] (row N = zeros). Output: bf16 [NS][N][32].
// Wave = 16 nodes x 4 lanes; lane (g,f) owns node g's feature-dwords 2f,2f+1 (8B gathers).
// Padded CSR: segments 8-aligned, pad entries = N_NODES (zero row) -> no masking.
// STREAMING accesses (csr loads, output stores) are NON-TEMPORAL so they don't evict the
// L2-resident slice; gathers use normal caching. csr prefetched one iteration ahead.
// NS==8: slice = blockIdx&7 (one XCD per slice, 3.2MB L2-resident).
// NS==4: slice = (blockIdx&7)&3, node range split across the XCD pairs.
#define ACC4(v)                                          \
    a0 += __builtin_amdgcn_cvt_pk_f32_fp8((int)v.x, false); \
    a1 += __builtin_amdgcn_cvt_pk_f32_fp8((int)v.x, true);  \
    a2 += __builtin_amdgcn_cvt_pk_f32_fp8((int)v.y, false); \
    a3 += __builtin_amdgcn_cvt_pk_f32_fp8((int)v.y, true);

template <int NS>
__global__ __launch_bounds__(512, 4) void csr_agg_p(
    const unsigned char* __restrict__ h, const int* __restrict__ pbeg,
    const int* __restrict__ pend, const int* __restrict__ csr,
    const float* __restrict__ dinv, unsigned short* __restrict__ out, int n) {
    int b7 = blockIdx.x & 7;
    int slice, node0;
    if (NS == 8) {
        slice = b7;
        node0 = (blockIdx.x >> 3) * 128;
    } else {
        slice = b7 & 3;
        node0 = (b7 >> 2) * (N_NODES / 2) + (blockIdx.x >> 3) * 128;
    }
    int wave = threadIdx.x >> 6, lane = threadIdx.x & 63;
    int g = lane >> 2, f = lane & 3;
    int node = node0 + wave * 16 + g;
    if (node >= n) return;
    int pb = pbeg[node], pe = pend[node];
    const unsigned char* hb = h + (size_t)slice * SIN;  // wave-uniform base
    unsigned int foff = (unsigned int)(f << 3);
    f32x2 a0 = {0.f, 0.f}, a1 = {0.f, 0.f}, a2 = {0.f, 0.f}, a3 = {0.f, 0.f};
    i32x4 sa = {0, 0, 0, 0}, sb = {0, 0, 0, 0};
    if (pb < pe) {
        sa = __builtin_nontemporal_load((const i32x4*)(csr + pb));
        sb = __builtin_nontemporal_load((const i32x4*)(csr + pb + 4));
    }
    for (int i = pb; i < pe; i += 8) {
        i32x4 na = __builtin_nontemporal_load((const i32x4*)(csr + i + 8));   // prefetch next
        i32x4 nb = __builtin_nontemporal_load((const i32x4*)(csr + i + 12));
        uint2 v0 = *(const uint2*)(hb + (((unsigned int)sa.x << 5) + foff));
        uint2 v1 = *(const uint2*)(hb + (((unsigned int)sa.y << 5) + foff));
        uint2 v2 = *(const uint2*)(hb + (((unsigned int)sa.z << 5) + foff));
        uint2 v3 = *(const uint2*)(hb + (((unsigned int)sa.w << 5) + foff));
        uint2 v4 = *(const uint2*)(hb + (((unsigned int)sb.x << 5) + foff));
        uint2 v5 = *(const uint2*)(hb + (((unsigned int)sb.y << 5) + foff));
        uint2 v6 = *(const uint2*)(hb + (((unsigned int)sb.z << 5) + foff));
        uint2 v7 = *(const uint2*)(hb + (((unsigned int)sb.w << 5) + foff));
        ACC4(v0) ACC4(v1) ACC4(v2) ACC4(v3)
        ACC4(v4) ACC4(v5) ACC4(v6) ACC4(v7)
        sa = na;
        sb = nb;
    }
    // self loop (pre-scaled by dinv at producer)
    uint2 sv = *(const uint2*)(hb + (((unsigned int)node << 5) + foff));
    ACC4(sv)
    float dn = dinv[node];
    u32x4 o;
    o.x = (unsigned int)f2bf(a0.x * dn) | ((unsigned int)f2bf(a0.y * dn) << 16);
    o.y = (unsigned int)f2bf(a1.x * dn) | ((unsigned int)f2bf(a1.y * dn) << 16);
    o.z = (unsigned int)f2bf(a2.x * dn) | ((unsigned int)f2bf(a2.y * dn) << 16);
    o.w = (unsigned int)f2bf(a3.x * dn) | ((unsigned int)f2bf(a3.y * dn) << 16);
    // 4 lanes x 16B = 64B contiguous per node-slice; nt store (no L2 pollution)
    __builtin_nontemporal_store(o, (u32x4*)(out + (size_t)slice * ASE + (size_t)node * 32 +
                                            (f << 3)));
}

// ---------------- MFMA GEMM: act(A[n,K] @ (Whi+Wlo) + b) ----------------
// A is SLICE-MAJOR bf16 [K/32][N][32]: k-tile kt == slice kt.
// block: 4 waves = 64 rows x 256 cols; wave: 32 rows (2 strips) x 128 cols (8 ct)
// MODE 0: out fp8 slice-major [8][N+1][32] = fp8(dinv[row]*relu(v))   (feeds agg<8>)
// MODE 2: out bf16 row-major [N][256] = bf16(relu(v))                 (feeds pooling)
template <int K, int MODE>
__global__ __launch_bounds__(256, 3) void gemm_mfma(
    const unsigned short* __restrict__ A, const unsigned short* __restrict__ Whi,
    const unsigned short* __restrict__ Wlo, const float* __restrict__ bias,
    const float* __restrict__ dinv, void* __restrict__ outp, int n) {
    int wave = threadIdx.x >> 6, lane = threadIdx.x & 63;
    int quad = lane >> 4, l16 = lane & 15;
    int rowgrp = wave >> 1, colhalf = wave & 1;
    int rowbase = blockIdx.x * 64 + rowgrp * 32;

    f32x4 acc[2][8];
#pragma unroll
    for (int s = 0; s < 2; s++)
#pragma unroll
        for (int ct = 0; ct < 8; ct++) acc[s][ct] = (f32x4){0.f, 0.f, 0.f, 0.f};

    int r0 = rowbase + l16;
    int r1 = rowbase + 16 + l16;
    int rc0 = r0 < n ? r0 : n - 1;
    int rc1 = r1 < n ? r1 : n - 1;

    for (int kt = 0; kt < K / 32; kt++) {
        bf16x8 a0 = *(const bf16x8*)(A + (size_t)kt * ASE + (size_t)rc0 * 32 + quad * 8);
        bf16x8 a1 = *(const bf16x8*)(A + (size_t)kt * ASE + (size_t)rc1 * 32 + quad * 8);
        const unsigned short* wh = Whi + ((size_t)kt * 16 + colhalf * 8) * 512 + lane * 8;
        const unsigned short* wl = Wlo + ((size_t)kt * 16 + colhalf * 8) * 512 + lane * 8;
#pragma unroll
        for (int ct = 0; ct < 8; ct++) {
            bf16x8 bh = *(const bf16x8*)(wh + ct * 512);
            bf16x8 bl = *(const bf16x8*)(wl + ct * 512);
            acc[0][ct] = __builtin_amdgcn_mfma_f32_16x16x32_bf16(a0, bh, acc[0][ct], 0, 0, 0);
            acc[0][ct] = __builtin_amdgcn_mfma_f32_16x16x32_bf16(a0, bl, acc[0][ct], 0, 0, 0);
            acc[1][ct] = __builtin_amdgcn_mfma_f32_16x16x32_bf16(a1, bh, acc[1][ct], 0, 0, 0);
            acc[1][ct] = __builtin_amdgcn_mfma_f32_16x16x32_bf16(a1, bl, acc[1][ct], 0, 0, 0);
        }
    }

#pragma unroll
    for (int s = 0; s < 2; s++) {
#pragma unroll
        for (int ct = 0; ct < 8; ct++) {
            int col = colhalf * 128 + ct * 16 + l16;
            float b = bias[col];
#pragma unroll
            for (int r = 0; r < 4; r++) {
                int row = rowbase + s * 16 + quad * 4 + r;
                if (row < n) {
                    float v = acc[s][ct][r] + b;
                    v = v > 0.0f ? v : 0.0f;
                    if (MODE == 0) {
                        ((unsigned char*)outp)[(size_t)(col >> 5) * SIN + (size_t)row * 32 +
                                               (col & 31)] = pack1_fp8(v * dinv[row]);
                    } else {
                        ((unsigned short*)outp)[(size_t)row * HDIM + col] = f2bf(v);
                    }
                }
            }
        }
    }
}

// ---------------- pooling (batch sorted -> run-length), bf16 input ----------------
__global__ void pool_sum_runs(const unsigned short* __restrict__ h, const int* __restrict__ batch,
                              float* __restrict__ pool, int n) {
    constexpr int ROWS = 128;
    int f = threadIdx.x;
    int r0 = blockIdx.x * ROWS;
    int rend = r0 + ROWS;
    if (rend > n) rend = n;
    float acc = 0.0f;
    int cur = batch[r0];
    for (int r = r0; r < rend; r++) {
        int g = batch[r];
        if (g != cur) {
            atomicAdd(&pool[cur * HDIM + f], acc);
            acc = 0.0f; cur = g;
        }
        acc += bf2f(h[(size_t)r * HDIM + f]);
    }
    atomicAdd(&pool[cur * HDIM + f], acc);
}

// ---------------- head: mean (cnt via binary search on sorted batch) + FC + log_softmax ----
__global__ void final_head(const float* __restrict__ pool, const int* __restrict__ batch,
                           const float* __restrict__ fcw, const float* __restrict__ fcb,
                           float* __restrict__ out, int n) {
    int g = threadIdx.x;
    if (g < N_GRAPHS) {
        int lo = 0, hi = n;
        while (lo < hi) { int m = (lo + hi) >> 1; if (batch[m] < g) lo = m + 1; else hi = m; }
        int b0 = lo;
        lo = 0; hi = n;
        while (lo < hi) { int m = (lo + hi) >> 1; if (batch[m] < g + 1) lo = m + 1; else hi = m; }
        int c = lo - b0;
        float cf = c > 1 ? (float)c : 1.0f;
        float inv = 1.0f / cf;
        float l0 = fcb[0], l1 = fcb[1];
        for (int f = 0; f < HDIM; f++) {
            float p = pool[g * HDIM + f] * inv;
            l0 += p * fcw[f * 2 + 0];
            l1 += p * fcw[f * 2 + 1];
        }
        float m = fmaxf(l0, l1);
        float lse = m + logf(expf(l0 - m) + expf(l1 - m));
        out[g * 2 + 0] = l0 - lse;
        out[g * 2 + 1] = l1 - lse;
    }
}

extern "C" void kernel_launch(void* const* d_in, const int* in_sizes, int n_in,
                              void* d_out, int out_size, void* d_ws, size_t ws_size,
                              hipStream_t stream) {
    const float* x = (const float*)d_in[0];
    const int* ei = (const int*)d_in[1];
    const int* batch = (const int*)d_in[2];
    const float* W1 = (const float*)d_in[3];
    const float* b1 = (const float*)d_in[4];
    const float* W2 = (const float*)d_in[5];
    const float* b2 = (const float*)d_in[6];
    const float* fcw = (const float*)d_in[7];
    const float* fcb = (const float*)d_in[8];
    float* out = (float*)d_out;

    const int* src = ei;
    const int* dst = ei + N_EDGES;

    // ---- workspace layout (bytes) ----
    char* ws = (char*)d_ws;
    float* dinv = (float*)ws;            ws += 4 * (size_t)NODE_PAD;
    int* deg = (int*)ws;                 ws += 4 * (size_t)NODE_PAD;
    int* pbeg = (int*)ws;                ws += 4 * (size_t)NODE_PAD;
    int* pend = (int*)ws;                ws += 4 * (size_t)NODE_PAD;
    int* csr_pad = (int*)ws;             ws += 4 * ((size_t)N_EDGES + 7 * N_NODES + 64);
    int* counts = (int*)ws;              ws += 4 * (size_t)NCHUNK * N_BUCKETS;
    int* offs = (int*)ws;                ws += 4 * (size_t)NCHUNK * N_BUCKETS;
    int* tot = (int*)ws;                 ws += 4 * 1024;
    int* bbase = (int*)ws;               ws += 4 * 1024;
    int* ptot = (int*)ws;                ws += 4 * 1024;
    int* pbase = (int*)ws;               ws += 4 * 1024;
    unsigned short* W1hi = (unsigned short*)ws; ws += 2 * F_IN * HDIM;
    unsigned short* W1lo = (unsigned short*)ws; ws += 2 * F_IN * HDIM;
    unsigned short* W2hi = (unsigned short*)ws; ws += 2 * HDIM * HDIM;
    unsigned short* W2lo = (unsigned short*)ws; ws += 2 * HDIM * HDIM;
    float* pool = (float*)ws;            ws += 4 * N_GRAPHS * HDIM;
    // R0 region (102.4MB): x_pre fp8 [4][N+1][32] | A1 bf16 [4][N][32] | h1_pre fp8 [8][N+1][32]
    // h2 [N][256] bf16 overlays R0 start (x_pre/A1/h1_pre dead by gemm2)
    char* R0 = ws;                       ws += 4 * (size_t)N_NODES * HDIM;
    unsigned char* x_pre = (unsigned char*)R0;
    unsigned short* A1 = (unsigned short*)(R0 + 12800256);          // 4*SIN=12800128, aligned 256
    unsigned char* h1_pre = (unsigned char*)(R0 + 12800256 + 2 * 4 * ASE);  // +25.6MB
    unsigned short* h2 = (unsigned short*)R0;
    unsigned short* A2 = (unsigned short*)ws;  // [8][N][32] bf16 (layer 2 only), 51.2MB
    // records overlay A2 (dead until layer 2): N_EDGES*4 = 12.8MB <= 51.2MB
    unsigned int* records = (unsigned int*)A2;

    // ---- atomic-free bucketed padded-CSR build + dinv ----
    block_count<<<NCHUNK, 256, 0, stream>>>(dst, counts, N_EDGES);
    bucket_totals<<<N_BUCKETS, 256, 0, stream>>>(counts, tot);
    scan_buckets<<<1, 1024, 0, stream>>>(tot, bbase, N_BUCKETS);
    column_scan<<<N_BUCKETS, 512, 0, stream>>>(counts, bbase, offs);
    block_scatter<<<NCHUNK, 256, 0, stream>>>(src, dst, offs, records, N_EDGES);
    bucket_csr_a<<<N_BUCKETS, 512, 0, stream>>>(records, bbase, deg, dinv, ptot, N_NODES);
    scan_buckets<<<1, 1024, 0, stream>>>(ptot, pbase, N_BUCKETS);
    bucket_csr_b<<<N_BUCKETS, 512, 0, stream>>>(records, bbase, deg, pbase, pbeg, pend,
                                                csr_pad, N_NODES);

    // ---- conversions / weight packing / zero inits ----
    zero_rows<<<1, 128, 0, stream>>>((unsigned int*)x_pre, (unsigned int*)h1_pre);
    convert_x_pre<<<(N_NODES * (F_IN / 4) + 255) / 256, 256, 0, stream>>>(
        x, dinv, (unsigned int*)x_pre, N_NODES);
    pack_w<<<(F_IN * HDIM + 255) / 256, 256, 0, stream>>>(W1, W1hi, W1lo, F_IN);
    pack_w<<<(HDIM * HDIM + 255) / 256, 256, 0, stream>>>(W2, W2hi, W2lo, HDIM);
    zero_f<<<(N_GRAPHS * HDIM + 255) / 256, 256, 0, stream>>>(pool, N_GRAPHS * HDIM);

    // ---- layer 1: 4 slices, node range split across XCD pairs ----
    csr_agg_p<4><<<((N_NODES / 2 + 127) / 128) * 8, 512, 0, stream>>>(
        x_pre, pbeg, pend, csr_pad, dinv, A1, N_NODES);
    gemm_mfma<F_IN, 0><<<(N_NODES + 63) / 64, 256, 0, stream>>>(A1, W1hi, W1lo, b1, dinv,
                                                                h1_pre, N_NODES);
    // ---- layer 2: 8 slices, one XCD per slice ----
    csr_agg_p<8><<<((N_NODES + 127) / 128) * 8, 512, 0, stream>>>(
        h1_pre, pbeg, pend, csr_pad, dinv, A2, N_NODES);
    gemm_mfma<HDIM, 2><<<(N_NODES + 63) / 64, 256, 0, stream>>>(A2, W2hi, W2lo, b2, dinv,
                                                                h2, N_NODES);

    // ---- pool + head ----
    pool_sum_runs<<<(N_NODES + 127) / 128, 256, 0, stream>>>(h2, batch, pool, N_NODES);
    final_head<<<1, 64, 0, stream>>>(pool, batch, fcw, fcb, out, N_NODES);
}

// Round 5
// 731.263 us; speedup vs baseline: 1.1378x; 1.1378x over previous
//
#include <hip/hip_runtime.h>
#include <cstdint>

#define N_NODES 100000
#define N_EDGES 3200000
#define N_GRAPHS 64
#define HDIM 256
#define F_IN 128

#define BUCKET_BITS 7
#define NPB 128                                 // nodes per bucket
#define N_BUCKETS ((N_NODES + NPB - 1) / NPB)   // 782
#define CHUNK 8192
#define NCHUNK ((N_EDGES + CHUNK - 1) / CHUNK)  // 391
#define NODE_PAD (N_BUCKETS * NPB)              // 100096 (bucket-aligned array size)

typedef __attribute__((ext_vector_type(8))) short bf16x8;
typedef __attribute__((ext_vector_type(4))) float f32x4;
typedef __attribute__((ext_vector_type(2))) float f32x2;
typedef __attribute__((ext_vector_type(4))) int i32x4;
typedef __attribute__((ext_vector_type(4))) unsigned int u32x4;

// fp8 slice row stride: (N+1) rows of 32B (row N is the zero row for CSR padding)
#define SIN ((size_t)(N_NODES + 1) * 32)
// bf16 slice-major A stride in ushort elements
#define ASE ((size_t)N_NODES * 32)

// ---------------- bf16 helpers ----------------
__device__ __forceinline__ unsigned short f2bf(float f) {
    unsigned int b = __float_as_uint(f);
    b = (b + 0x7FFFu + ((b >> 16) & 1u)) >> 16;
    return (unsigned short)b;
}
__device__ __forceinline__ float bf2f(unsigned short u) {
    return __uint_as_float((unsigned int)u << 16);
}

// ---------------- fp8 e4m3 helpers (HW cvt) ----------------
__device__ __forceinline__ unsigned int pack4_fp8(float a, float b, float c, float d) {
    int v = 0;
    v = __builtin_amdgcn_cvt_pk_fp8_f32(a, b, v, false);  // bytes 0,1
    v = __builtin_amdgcn_cvt_pk_fp8_f32(c, d, v, true);   // bytes 2,3
    return (unsigned int)v;
}
__device__ __forceinline__ unsigned char pack1_fp8(float a) {
    int v = __builtin_amdgcn_cvt_pk_fp8_f32(a, a, 0, false);
    return (unsigned char)(v & 0xFF);
}

// ---------------- utility ----------------
__global__ void zero_f(float* p, int n) {
    int i = blockIdx.x * blockDim.x + threadIdx.x;
    if (i < n) p[i] = 0.0f;
}

// zero the pad rows (index N_NODES) of the fp8 slice buffers
__global__ void zero_rows(unsigned int* xp, unsigned int* hp) {
    int t = threadIdx.x;
    if (t < 32)  // 4 slices x 8 dwords
        xp[(size_t)(t >> 3) * ((size_t)(N_NODES + 1) * 8) + (size_t)N_NODES * 8 + (t & 7)] = 0;
    if (t >= 32 && t < 96) {  // 8 slices x 8 dwords
        int u = t - 32;
        hp[(size_t)(u >> 3) * ((size_t)(N_NODES + 1) * 8) + (size_t)N_NODES * 8 + (u & 7)] = 0;
    }
}

// ---------------- atomic-free multisplit CSR build ----------------
__global__ __launch_bounds__(256) void block_count(const int* __restrict__ dst,
                                                   int* __restrict__ counts, int nE) {
    __shared__ int hist[N_BUCKETS];
    int blk = blockIdx.x, t = threadIdx.x;
    for (int i = t; i < N_BUCKETS; i += 256) hist[i] = 0;
    __syncthreads();
    int lo = blk * CHUNK;
    int hi = lo + CHUNK < nE ? lo + CHUNK : nE;
    for (int i = lo + t; i < hi; i += 256) atomicAdd(&hist[dst[i] >> BUCKET_BITS], 1);
    __syncthreads();
    for (int i = t; i < N_BUCKETS; i += 256) counts[blk * N_BUCKETS + i] = hist[i];
}

__global__ __launch_bounds__(256) void bucket_totals(const int* __restrict__ counts,
                                                     int* __restrict__ tot) {
    __shared__ int red[256];
    int b = blockIdx.x, t = threadIdx.x;
    int s = 0;
    for (int blk = t; blk < NCHUNK; blk += 256) s += counts[blk * N_BUCKETS + b];
    red[t] = s;
    __syncthreads();
    for (int o = 128; o > 0; o >>= 1) {
        if (t < o) red[t] += red[t + o];
        __syncthreads();
    }
    if (t == 0) tot[b] = red[0];
}

__global__ __launch_bounds__(1024) void scan_buckets(const int* __restrict__ tot,
                                                     int* __restrict__ base, int nb) {
    __shared__ int lds[1024];
    int t = threadIdx.x;
    int v = (t < nb) ? tot[t] : 0;
    lds[t] = v;
    __syncthreads();
    for (int off = 1; off < 1024; off <<= 1) {
        int a = (t >= off) ? lds[t - off] : 0;
        __syncthreads();
        lds[t] += a;
        __syncthreads();
    }
    int excl = lds[t] - v;
    if (t < nb) base[t] = excl;
    if (t == nb) base[t] = excl;
}

__global__ __launch_bounds__(512) void column_scan(const int* __restrict__ counts,
                                                   const int* __restrict__ base,
                                                   int* __restrict__ offs) {
    __shared__ int lds[512];
    int b = blockIdx.x, t = threadIdx.x;
    int v = (t < NCHUNK) ? counts[t * N_BUCKETS + b] : 0;
    lds[t] = v;
    __syncthreads();
    for (int off = 1; off < 512; off <<= 1) {
        int a = (t >= off) ? lds[t - off] : 0;
        __syncthreads();
        lds[t] += a;
        __syncthreads();
    }
    if (t < NCHUNK) offs[t * N_BUCKETS + b] = base[b] + lds[t] - v;
}

__global__ __launch_bounds__(256) void block_scatter(const int* __restrict__ src,
                                                     const int* __restrict__ dst,
                                                     const int* __restrict__ offs,
                                                     unsigned int* __restrict__ rec, int nE) {
    __shared__ int cur[N_BUCKETS];
    int blk = blockIdx.x, t = threadIdx.x;
    for (int i = t; i < N_BUCKETS; i += 256) cur[i] = offs[blk * N_BUCKETS + i];
    __syncthreads();
    int lo = blk * CHUNK;
    int hi = lo + CHUNK < nE ? lo + CHUNK : nE;
    for (int i = lo + t; i < hi; i += 256) {
        int d = dst[i];
        int b = d >> BUCKET_BITS;
        int pos = atomicAdd(&cur[b], 1);  // LDS atomic
        rec[pos] = (unsigned int)src[i] | ((unsigned int)(d & (NPB - 1)) << 17);
    }
}

// Phase A: per-node degree + dinv + per-bucket padded totals
__global__ __launch_bounds__(512) void bucket_csr_a(const unsigned int* __restrict__ rec,
                                                    const int* __restrict__ base,
                                                    int* __restrict__ deg,
                                                    float* __restrict__ dinv,
                                                    int* __restrict__ ptot, int n) {
    __shared__ int hist[NPB];
    __shared__ int red[NPB];
    int b = blockIdx.x;
    int lo = base[b], hi = base[b + 1];
    int t = threadIdx.x;
    if (t < NPB) hist[t] = 0;
    __syncthreads();
    for (int i = lo + t; i < hi; i += 512) atomicAdd(&hist[rec[i] >> 17], 1);
    __syncthreads();
    if (t < NPB) {
        int node = b * NPB + t;
        int dg = hist[t];  // nodes >= n never occur in rec -> dg == 0
        deg[node] = dg;
        dinv[node] = rsqrtf((float)dg + 1.0f);
        red[t] = (dg + 7) & ~7;
    }
    __syncthreads();
    for (int o = 64; o > 0; o >>= 1) {
        if (t < o) red[t] += red[t + o];
        __syncthreads();
    }
    if (t == 0) ptot[b] = red[0];
}

// Phase B: padded per-node segments; scatter edges; fill pad slots with zero-node (n)
__global__ __launch_bounds__(512) void bucket_csr_b(const unsigned int* __restrict__ rec,
                                                    const int* __restrict__ base,
                                                    const int* __restrict__ deg,
                                                    const int* __restrict__ pbase,
                                                    int* __restrict__ pbeg, int* __restrict__ pend,
                                                    int* __restrict__ cpad, int n) {
    __shared__ int sc[NPB];
    __shared__ int cur[NPB];
    int b = blockIdx.x;
    int lo = base[b], hi = base[b + 1];
    int t = threadIdx.x;
    int dg = 0, pdg = 0;
    if (t < NPB) {
        dg = deg[b * NPB + t];
        pdg = (dg + 7) & ~7;
        sc[t] = pdg;
    }
    __syncthreads();
    for (int off = 1; off < NPB; off <<= 1) {
        int a = (t < NPB && t >= off) ? sc[t - off] : 0;
        __syncthreads();
        if (t < NPB) sc[t] += a;
        __syncthreads();
    }
    int pos0 = 0;
    if (t < NPB) {
        pos0 = pbase[b] + sc[t] - pdg;
        int node = b * NPB + t;
        if (node < n) {
            pbeg[node] = pos0;
            pend[node] = pos0 + pdg;
        }
        cur[t] = pos0;
    }
    __syncthreads();
    for (int i = lo + t; i < hi; i += 512) {
        unsigned int r = rec[i];
        int pos = atomicAdd(&cur[r >> 17], 1);
        cpad[pos] = (int)(r & 0x1FFFFu);
    }
    // fill pad slots (disjoint from scattered region; no sync needed)
    if (t < NPB) {
        for (int p = pos0 + dg; p < pos0 + pdg; p++) cpad[p] = n;  // zero-node index
    }
}

// ---------------- x -> fp8 pre-scaled, SLICE-MAJOR: xp[slice][node][8 dwords] ----------------
__global__ void convert_x_pre(const float* __restrict__ x, const float* __restrict__ dinv,
                              unsigned int* __restrict__ xp, int n) {
    int tid = blockIdx.x * blockDim.x + threadIdx.x;  // over n*F_IN/4 dword groups
    if (tid >= n * (F_IN / 4)) return;
    int node = tid >> 5;  // F_IN/4 = 32 dwords per node
    int d = tid & 31;     // dword within node; slice = d>>3
    float di = dinv[node];
    float4 v = ((const float4*)x)[tid];
    xp[(size_t)(d >> 3) * ((size_t)(N_NODES + 1) * 8) + (size_t)node * 8 + (d & 7)] =
        pack4_fp8(v.x * di, v.y * di, v.z * di, v.w * di);
}

// ---------------- pack W[K][256] fp32 -> hi/lo bf16 in MFMA B-fragment order ----------------
__global__ void pack_w(const float* __restrict__ W, unsigned short* __restrict__ hi,
                       unsigned short* __restrict__ lo, int K) {
    int idx = blockIdx.x * blockDim.x + threadIdx.x;
    if (idx >= K * HDIM) return;
    int k = idx >> 8, c = idx & 255;
    float w = W[idx];
    unsigned short h = f2bf(w);
    float hf = __uint_as_float((unsigned int)h << 16);
    unsigned short l = f2bf(w - hf);
    int pos = ((k >> 5) * 16 + (c >> 4)) * 512 + ((((k >> 3) & 3) * 16) + (c & 15)) * 8 + (k & 7);
    hi[pos] = h;
    lo[pos] = l;
}

// ---------------- XCD-pinned feature-sliced aggregation, padded CSR, 16B gathers ------------
// Input h: fp8, slice-major [NS][N+1][32B] (row N = zeros). Output: bf16 [NS][N][32].
// Wave = 32 nodes x 2 lanes; lane (g,f) owns node g's 16B half-row f (16 features) end-to-end:
// 2 addresses per 32B row (halves TA address pressure vs 4x8B), no cross-lane combine.
// Padded CSR: segments 8-aligned, pad entries = N_NODES (zero row) -> no masking.
// csr prefetched one iteration ahead. All loads/stores NORMAL caching (nt hurt: R4).
// NS==8: slice = blockIdx&7 (one XCD per slice, 3.2MB L2-resident).
// NS==4: slice = (blockIdx&7)&3, node range split across the XCD pairs.
#define ACC8(v)                                             \
    a0 += __builtin_amdgcn_cvt_pk_f32_fp8((int)v.x, false); \
    a1 += __builtin_amdgcn_cvt_pk_f32_fp8((int)v.x, true);  \
    a2 += __builtin_amdgcn_cvt_pk_f32_fp8((int)v.y, false); \
    a3 += __builtin_amdgcn_cvt_pk_f32_fp8((int)v.y, true);  \
    a4 += __builtin_amdgcn_cvt_pk_f32_fp8((int)v.z, false); \
    a5 += __builtin_amdgcn_cvt_pk_f32_fp8((int)v.z, true);  \
    a6 += __builtin_amdgcn_cvt_pk_f32_fp8((int)v.w, false); \
    a7 += __builtin_amdgcn_cvt_pk_f32_fp8((int)v.w, true);

template <int NS>
__global__ __launch_bounds__(512, 3) void csr_agg_p(
    const unsigned char* __restrict__ h, const int* __restrict__ pbeg,
    const int* __restrict__ pend, const int* __restrict__ csr,
    const float* __restrict__ dinv, unsigned short* __restrict__ out, int n) {
    int b7 = blockIdx.x & 7;
    int slice, node0;
    if (NS == 8) {
        slice = b7;
        node0 = (blockIdx.x >> 3) * 256;
    } else {
        slice = b7 & 3;
        node0 = (b7 >> 2) * (N_NODES / 2) + (blockIdx.x >> 3) * 256;
    }
    int wave = threadIdx.x >> 6, lane = threadIdx.x & 63;
    int g = lane >> 1, f = lane & 1;
    int node = node0 + wave * 32 + g;
    if (node >= n) return;
    int pb = pbeg[node], pe = pend[node];
    const unsigned char* hb = h + (size_t)slice * SIN;  // wave-uniform base
    unsigned int foff = (unsigned int)(f << 4);
    f32x2 a0 = {0.f, 0.f}, a1 = {0.f, 0.f}, a2 = {0.f, 0.f}, a3 = {0.f, 0.f};
    f32x2 a4 = {0.f, 0.f}, a5 = {0.f, 0.f}, a6 = {0.f, 0.f}, a7 = {0.f, 0.f};
    i32x4 sa = {0, 0, 0, 0}, sb = {0, 0, 0, 0};
    if (pb < pe) {
        sa = *(const i32x4*)(csr + pb);
        sb = *(const i32x4*)(csr + pb + 4);
    }
    for (int i = pb; i < pe; i += 8) {
        i32x4 na = *(const i32x4*)(csr + i + 8);   // prefetch next (over-read padded)
        i32x4 nb = *(const i32x4*)(csr + i + 12);
        u32x4 v0 = *(const u32x4*)(hb + (((unsigned int)sa.x << 5) + foff));
        u32x4 v1 = *(const u32x4*)(hb + (((unsigned int)sa.y << 5) + foff));
        u32x4 v2 = *(const u32x4*)(hb + (((unsigned int)sa.z << 5) + foff));
        u32x4 v3 = *(const u32x4*)(hb + (((unsigned int)sa.w << 5) + foff));
        u32x4 v4 = *(const u32x4*)(hb + (((unsigned int)sb.x << 5) + foff));
        u32x4 v5 = *(const u32x4*)(hb + (((unsigned int)sb.y << 5) + foff));
        u32x4 v6 = *(const u32x4*)(hb + (((unsigned int)sb.z << 5) + foff));
        u32x4 v7 = *(const u32x4*)(hb + (((unsigned int)sb.w << 5) + foff));
        ACC8(v0) ACC8(v1) ACC8(v2) ACC8(v3)
        ACC8(v4) ACC8(v5) ACC8(v6) ACC8(v7)
        sa = na;
        sb = nb;
    }
    // self loop (pre-scaled by dinv at producer)
    u32x4 sv = *(const u32x4*)(hb + (((unsigned int)node << 5) + foff));
    ACC8(sv)
    float dn = dinv[node];
    u32x4 o1, o2;
    o1.x = (unsigned int)f2bf(a0.x * dn) | ((unsigned int)f2bf(a0.y * dn) << 16);
    o1.y = (unsigned int)f2bf(a1.x * dn) | ((unsigned int)f2bf(a1.y * dn) << 16);
    o1.z = (unsigned int)f2bf(a2.x * dn) | ((unsigned int)f2bf(a2.y * dn) << 16);
    o1.w = (unsigned int)f2bf(a3.x * dn) | ((unsigned int)f2bf(a3.y * dn) << 16);
    o2.x = (unsigned int)f2bf(a4.x * dn) | ((unsigned int)f2bf(a4.y * dn) << 16);
    o2.y = (unsigned int)f2bf(a5.x * dn) | ((unsigned int)f2bf(a5.y * dn) << 16);
    o2.z = (unsigned int)f2bf(a6.x * dn) | ((unsigned int)f2bf(a6.y * dn) << 16);
    o2.w = (unsigned int)f2bf(a7.x * dn) | ((unsigned int)f2bf(a7.y * dn) << 16);
    // 2 lanes x 32B = 64B contiguous per node-slice
    unsigned short* ob = out + (size_t)slice * ASE + (size_t)node * 32 + (f << 4);
    *(u32x4*)ob = o1;
    *(u32x4*)(ob + 8) = o2;
}

// ---------------- MFMA GEMM: act(A[n,K] @ (Whi+Wlo) + b) ----------------
// A is SLICE-MAJOR bf16 [K/32][N][32]: k-tile kt == slice kt.
// block: 4 waves = 64 rows x 256 cols; wave: 32 rows (2 strips) x 128 cols (8 ct)
// MODE 0: out fp8 slice-major [8][N+1][32] = fp8(dinv[row]*relu(v))   (feeds agg<8>)
// MODE 2: out bf16 row-major [N][256] = bf16(relu(v))                 (feeds pooling)
template <int K, int MODE>
__global__ __launch_bounds__(256, 3) void gemm_mfma(
    const unsigned short* __restrict__ A, const unsigned short* __restrict__ Whi,
    const unsigned short* __restrict__ Wlo, const float* __restrict__ bias,
    const float* __restrict__ dinv, void* __restrict__ outp, int n) {
    int wave = threadIdx.x >> 6, lane = threadIdx.x & 63;
    int quad = lane >> 4, l16 = lane & 15;
    int rowgrp = wave >> 1, colhalf = wave & 1;
    int rowbase = blockIdx.x * 64 + rowgrp * 32;

    f32x4 acc[2][8];
#pragma unroll
    for (int s = 0; s < 2; s++)
#pragma unroll
        for (int ct = 0; ct < 8; ct++) acc[s][ct] = (f32x4){0.f, 0.f, 0.f, 0.f};

    int r0 = rowbase + l16;
    int r1 = rowbase + 16 + l16;
    int rc0 = r0 < n ? r0 : n - 1;
    int rc1 = r1 < n ? r1 : n - 1;

    for (int kt = 0; kt < K / 32; kt++) {
        bf16x8 a0 = *(const bf16x8*)(A + (size_t)kt * ASE + (size_t)rc0 * 32 + quad * 8);
        bf16x8 a1 = *(const bf16x8*)(A + (size_t)kt * ASE + (size_t)rc1 * 32 + quad * 8);
        const unsigned short* wh = Whi + ((size_t)kt * 16 + colhalf * 8) * 512 + lane * 8;
        const unsigned short* wl = Wlo + ((size_t)kt * 16 + colhalf * 8) * 512 + lane * 8;
#pragma unroll
        for (int ct = 0; ct < 8; ct++) {
            bf16x8 bh = *(const bf16x8*)(wh + ct * 512);
            bf16x8 bl = *(const bf16x8*)(wl + ct * 512);
            acc[0][ct] = __builtin_amdgcn_mfma_f32_16x16x32_bf16(a0, bh, acc[0][ct], 0, 0, 0);
            acc[0][ct] = __builtin_amdgcn_mfma_f32_16x16x32_bf16(a0, bl, acc[0][ct], 0, 0, 0);
            acc[1][ct] = __builtin_amdgcn_mfma_f32_16x16x32_bf16(a1, bh, acc[1][ct], 0, 0, 0);
            acc[1][ct] = __builtin_amdgcn_mfma_f32_16x16x32_bf16(a1, bl, acc[1][ct], 0, 0, 0);
        }
    }

#pragma unroll
    for (int s = 0; s < 2; s++) {
#pragma unroll
        for (int ct = 0; ct < 8; ct++) {
            int col = colhalf * 128 + ct * 16 + l16;
            float b = bias[col];
#pragma unroll
            for (int r = 0; r < 4; r++) {
                int row = rowbase + s * 16 + quad * 4 + r;
                if (row < n) {
                    float v = acc[s][ct][r] + b;
                    v = v > 0.0f ? v : 0.0f;
                    if (MODE == 0) {
                        ((unsigned char*)outp)[(size_t)(col >> 5) * SIN + (size_t)row * 32 +
                                               (col & 31)] = pack1_fp8(v * dinv[row]);
                    } else {
                        ((unsigned short*)outp)[(size_t)row * HDIM + col] = f2bf(v);
                    }
                }
            }
        }
    }
}

// ---------------- pooling (batch sorted -> run-length), bf16 input ----------------
__global__ void pool_sum_runs(const unsigned short* __restrict__ h, const int* __restrict__ batch,
                              float* __restrict__ pool, int n) {
    constexpr int ROWS = 128;
    int f = threadIdx.x;
    int r0 = blockIdx.x * ROWS;
    int rend = r0 + ROWS;
    if (rend > n) rend = n;
    float acc = 0.0f;
    int cur = batch[r0];
    for (int r = r0; r < rend; r++) {
        int g = batch[r];
        if (g != cur) {
            atomicAdd(&pool[cur * HDIM + f], acc);
            acc = 0.0f; cur = g;
        }
        acc += bf2f(h[(size_t)r * HDIM + f]);
    }
    atomicAdd(&pool[cur * HDIM + f], acc);
}

// ---------------- head: mean (cnt via binary search on sorted batch) + FC + log_softmax ----
__global__ void final_head(const float* __restrict__ pool, const int* __restrict__ batch,
                           const float* __restrict__ fcw, const float* __restrict__ fcb,
                           float* __restrict__ out, int n) {
    int g = threadIdx.x;
    if (g < N_GRAPHS) {
        int lo = 0, hi = n;
        while (lo < hi) { int m = (lo + hi) >> 1; if (batch[m] < g) lo = m + 1; else hi = m; }
        int b0 = lo;
        lo = 0; hi = n;
        while (lo < hi) { int m = (lo + hi) >> 1; if (batch[m] < g + 1) lo = m + 1; else hi = m; }
        int c = lo - b0;
        float cf = c > 1 ? (float)c : 1.0f;
        float inv = 1.0f / cf;
        float l0 = fcb[0], l1 = fcb[1];
        for (int f = 0; f < HDIM; f++) {
            float p = pool[g * HDIM + f] * inv;
            l0 += p * fcw[f * 2 + 0];
            l1 += p * fcw[f * 2 + 1];
        }
        float m = fmaxf(l0, l1);
        float lse = m + logf(expf(l0 - m) + expf(l1 - m));
        out[g * 2 + 0] = l0 - lse;
        out[g * 2 + 1] = l1 - lse;
    }
}

extern "C" void kernel_launch(void* const* d_in, const int* in_sizes, int n_in,
                              void* d_out, int out_size, void* d_ws, size_t ws_size,
                              hipStream_t stream) {
    const float* x = (const float*)d_in[0];
    const int* ei = (const int*)d_in[1];
    const int* batch = (const int*)d_in[2];
    const float* W1 = (const float*)d_in[3];
    const float* b1 = (const float*)d_in[4];
    const float* W2 = (const float*)d_in[5];
    const float* b2 = (const float*)d_in[6];
    const float* fcw = (const float*)d_in[7];
    const float* fcb = (const float*)d_in[8];
    float* out = (float*)d_out;

    const int* src = ei;
    const int* dst = ei + N_EDGES;

    // ---- workspace layout (bytes) ----
    char* ws = (char*)d_ws;
    float* dinv = (float*)ws;            ws += 4 * (size_t)NODE_PAD;
    int* deg = (int*)ws;                 ws += 4 * (size_t)NODE_PAD;
    int* pbeg = (int*)ws;                ws += 4 * (size_t)NODE_PAD;
    int* pend = (int*)ws;                ws += 4 * (size_t)NODE_PAD;
    int* csr_pad = (int*)ws;             ws += 4 * ((size_t)N_EDGES + 7 * N_NODES + 64);
    int* counts = (int*)ws;              ws += 4 * (size_t)NCHUNK * N_BUCKETS;
    int* offs = (int*)ws;                ws += 4 * (size_t)NCHUNK * N_BUCKETS;
    int* tot = (int*)ws;                 ws += 4 * 1024;
    int* bbase = (int*)ws;               ws += 4 * 1024;
    int* ptot = (int*)ws;                ws += 4 * 1024;
    int* pbase = (int*)ws;               ws += 4 * 1024;
    unsigned short* W1hi = (unsigned short*)ws; ws += 2 * F_IN * HDIM;
    unsigned short* W1lo = (unsigned short*)ws; ws += 2 * F_IN * HDIM;
    unsigned short* W2hi = (unsigned short*)ws; ws += 2 * HDIM * HDIM;
    unsigned short* W2lo = (unsigned short*)ws; ws += 2 * HDIM * HDIM;
    float* pool = (float*)ws;            ws += 4 * N_GRAPHS * HDIM;
    // R0 region (102.4MB): x_pre fp8 [4][N+1][32] | A1 bf16 [4][N][32] | h1_pre fp8 [8][N+1][32]
    // h2 [N][256] bf16 overlays R0 start (x_pre/A1/h1_pre dead by gemm2)
    char* R0 = ws;                       ws += 4 * (size_t)N_NODES * HDIM;
    unsigned char* x_pre = (unsigned char*)R0;
    unsigned short* A1 = (unsigned short*)(R0 + 12800256);          // 4*SIN=12800128, aligned 256
    unsigned char* h1_pre = (unsigned char*)(R0 + 12800256 + 2 * 4 * ASE);  // +25.6MB
    unsigned short* h2 = (unsigned short*)R0;
    unsigned short* A2 = (unsigned short*)ws;  // [8][N][32] bf16 (layer 2 only), 51.2MB
    // records overlay A2 (dead until layer 2): N_EDGES*4 = 12.8MB <= 51.2MB
    unsigned int* records = (unsigned int*)A2;

    // ---- atomic-free bucketed padded-CSR build + dinv ----
    block_count<<<NCHUNK, 256, 0, stream>>>(dst, counts, N_EDGES);
    bucket_totals<<<N_BUCKETS, 256, 0, stream>>>(counts, tot);
    scan_buckets<<<1, 1024, 0, stream>>>(tot, bbase, N_BUCKETS);
    column_scan<<<N_BUCKETS, 512, 0, stream>>>(counts, bbase, offs);
    block_scatter<<<NCHUNK, 256, 0, stream>>>(src, dst, offs, records, N_EDGES);
    bucket_csr_a<<<N_BUCKETS, 512, 0, stream>>>(records, bbase, deg, dinv, ptot, N_NODES);
    scan_buckets<<<1, 1024, 0, stream>>>(ptot, pbase, N_BUCKETS);
    bucket_csr_b<<<N_BUCKETS, 512, 0, stream>>>(records, bbase, deg, pbase, pbeg, pend,
                                                csr_pad, N_NODES);

    // ---- conversions / weight packing / zero inits ----
    zero_rows<<<1, 128, 0, stream>>>((unsigned int*)x_pre, (unsigned int*)h1_pre);
    convert_x_pre<<<(N_NODES * (F_IN / 4) + 255) / 256, 256, 0, stream>>>(
        x, dinv, (unsigned int*)x_pre, N_NODES);
    pack_w<<<(F_IN * HDIM + 255) / 256, 256, 0, stream>>>(W1, W1hi, W1lo, F_IN);
    pack_w<<<(HDIM * HDIM + 255) / 256, 256, 0, stream>>>(W2, W2hi, W2lo, HDIM);
    zero_f<<<(N_GRAPHS * HDIM + 255) / 256, 256, 0, stream>>>(pool, N_GRAPHS * HDIM);

    // ---- layer 1: 4 slices, node range split across XCD pairs ----
    csr_agg_p<4><<<((N_NODES / 2 + 255) / 256) * 8, 512, 0, stream>>>(
        x_pre, pbeg, pend, csr_pad, dinv, A1, N_NODES);
    gemm_mfma<F_IN, 0><<<(N_NODES + 63) / 64, 256, 0, stream>>>(A1, W1hi, W1lo, b1, dinv,
                                                                h1_pre, N_NODES);
    // ---- layer 2: 8 slices, one XCD per slice ----
    csr_agg_p<8><<<((N_NODES + 255) / 256) * 8, 512, 0, stream>>>(
        h1_pre, pbeg, pend, csr_pad, dinv, A2, N_NODES);
    gemm_mfma<HDIM, 2><<<(N_NODES + 63) / 64, 256, 0, stream>>>(A2, W2hi, W2lo, b2, dinv,
                                                                h2, N_NODES);

    // ---- pool + head ----
    pool_sum_runs<<<(N_NODES + 127) / 128, 256, 0, stream>>>(h2, batch, pool, N_NODES);
    final_head<<<1, 64, 0, stream>>>(pool, batch, fcw, fcb, out, N_NODES);
}

// Round 6
// 670.855 us; speedup vs baseline: 1.2403x; 1.0900x over previous
//
#include <hip/hip_runtime.h>
#include <cstdint>

#define N_NODES 100000
#define N_EDGES 3200000
#define N_GRAPHS 64
#define HDIM 256
#define F_IN 128

#define BUCKET_BITS 7
#define NPB 128                                 // nodes per bucket
#define N_BUCKETS ((N_NODES + NPB - 1) / NPB)   // 782
#define CHUNK 8192
#define NCHUNK ((N_EDGES + CHUNK - 1) / CHUNK)  // 391
#define NODE_PAD (N_BUCKETS * NPB)              // 100096 (bucket-aligned array size)

#define LDS_INTS 8192                           // 32KB csr stage buffer per block

typedef __attribute__((ext_vector_type(8))) short bf16x8;
typedef __attribute__((ext_vector_type(4))) float f32x4;
typedef __attribute__((ext_vector_type(2))) float f32x2;
typedef __attribute__((ext_vector_type(4))) int i32x4;
typedef __attribute__((ext_vector_type(4))) unsigned int u32x4;

// fp8 slice row stride: (N+1) rows of 32B (row N is the zero row for CSR padding)
#define SIN ((size_t)(N_NODES + 1) * 32)
// bf16 slice-major A stride in ushort elements
#define ASE ((size_t)N_NODES * 32)

// ---------------- bf16 helpers ----------------
__device__ __forceinline__ unsigned short f2bf(float f) {
    unsigned int b = __float_as_uint(f);
    b = (b + 0x7FFFu + ((b >> 16) & 1u)) >> 16;
    return (unsigned short)b;
}
__device__ __forceinline__ float bf2f(unsigned short u) {
    return __uint_as_float((unsigned int)u << 16);
}

// ---------------- fp8 e4m3 helpers (HW cvt) ----------------
__device__ __forceinline__ unsigned int pack4_fp8(float a, float b, float c, float d) {
    int v = 0;
    v = __builtin_amdgcn_cvt_pk_fp8_f32(a, b, v, false);  // bytes 0,1
    v = __builtin_amdgcn_cvt_pk_fp8_f32(c, d, v, true);   // bytes 2,3
    return (unsigned int)v;
}
__device__ __forceinline__ unsigned char pack1_fp8(float a) {
    int v = __builtin_amdgcn_cvt_pk_fp8_f32(a, a, 0, false);
    return (unsigned char)(v & 0xFF);
}

// ---------------- utility ----------------
__global__ void zero_f(float* p, int n) {
    int i = blockIdx.x * blockDim.x + threadIdx.x;
    if (i < n) p[i] = 0.0f;
}

// zero the pad rows (index N_NODES) of the fp8 slice buffers
__global__ void zero_rows(unsigned int* xp, unsigned int* hp) {
    int t = threadIdx.x;
    if (t < 32)  // 4 slices x 8 dwords
        xp[(size_t)(t >> 3) * ((size_t)(N_NODES + 1) * 8) + (size_t)N_NODES * 8 + (t & 7)] = 0;
    if (t >= 32 && t < 96) {  // 8 slices x 8 dwords
        int u = t - 32;
        hp[(size_t)(u >> 3) * ((size_t)(N_NODES + 1) * 8) + (size_t)N_NODES * 8 + (u & 7)] = 0;
    }
}

// ---------------- atomic-free multisplit CSR build ----------------
__global__ __launch_bounds__(256) void block_count(const int* __restrict__ dst,
                                                   int* __restrict__ counts, int nE) {
    __shared__ int hist[N_BUCKETS];
    int blk = blockIdx.x, t = threadIdx.x;
    for (int i = t; i < N_BUCKETS; i += 256) hist[i] = 0;
    __syncthreads();
    int lo = blk * CHUNK;
    int hi = lo + CHUNK < nE ? lo + CHUNK : nE;
    for (int i = lo + t; i < hi; i += 256) atomicAdd(&hist[dst[i] >> BUCKET_BITS], 1);
    __syncthreads();
    for (int i = t; i < N_BUCKETS; i += 256) counts[blk * N_BUCKETS + i] = hist[i];
}

__global__ __launch_bounds__(256) void bucket_totals(const int* __restrict__ counts,
                                                     int* __restrict__ tot) {
    __shared__ int red[256];
    int b = blockIdx.x, t = threadIdx.x;
    int s = 0;
    for (int blk = t; blk < NCHUNK; blk += 256) s += counts[blk * N_BUCKETS + b];
    red[t] = s;
    __syncthreads();
    for (int o = 128; o > 0; o >>= 1) {
        if (t < o) red[t] += red[t + o];
        __syncthreads();
    }
    if (t == 0) tot[b] = red[0];
}

__global__ __launch_bounds__(1024) void scan_buckets(const int* __restrict__ tot,
                                                     int* __restrict__ base, int nb) {
    __shared__ int lds[1024];
    int t = threadIdx.x;
    int v = (t < nb) ? tot[t] : 0;
    lds[t] = v;
    __syncthreads();
    for (int off = 1; off < 1024; off <<= 1) {
        int a = (t >= off) ? lds[t - off] : 0;
        __syncthreads();
        lds[t] += a;
        __syncthreads();
    }
    int excl = lds[t] - v;
    if (t < nb) base[t] = excl;
    if (t == nb) base[t] = excl;
}

__global__ __launch_bounds__(512) void column_scan(const int* __restrict__ counts,
                                                   const int* __restrict__ base,
                                                   int* __restrict__ offs) {
    __shared__ int lds[512];
    int b = blockIdx.x, t = threadIdx.x;
    int v = (t < NCHUNK) ? counts[t * N_BUCKETS + b] : 0;
    lds[t] = v;
    __syncthreads();
    for (int off = 1; off < 512; off <<= 1) {
        int a = (t >= off) ? lds[t - off] : 0;
        __syncthreads();
        lds[t] += a;
        __syncthreads();
    }
    if (t < NCHUNK) offs[t * N_BUCKETS + b] = base[b] + lds[t] - v;
}

__global__ __launch_bounds__(256) void block_scatter(const int* __restrict__ src,
                                                     const int* __restrict__ dst,
                                                     const int* __restrict__ offs,
                                                     unsigned int* __restrict__ rec, int nE) {
    __shared__ int cur[N_BUCKETS];
    int blk = blockIdx.x, t = threadIdx.x;
    for (int i = t; i < N_BUCKETS; i += 256) cur[i] = offs[blk * N_BUCKETS + i];
    __syncthreads();
    int lo = blk * CHUNK;
    int hi = lo + CHUNK < nE ? lo + CHUNK : nE;
    for (int i = lo + t; i < hi; i += 256) {
        int d = dst[i];
        int b = d >> BUCKET_BITS;
        int pos = atomicAdd(&cur[b], 1);  // LDS atomic
        rec[pos] = (unsigned int)src[i] | ((unsigned int)(d & (NPB - 1)) << 17);
    }
}

// Phase A: per-node degree + dinv + per-bucket padded totals
__global__ __launch_bounds__(512) void bucket_csr_a(const unsigned int* __restrict__ rec,
                                                    const int* __restrict__ base,
                                                    int* __restrict__ deg,
                                                    float* __restrict__ dinv,
                                                    int* __restrict__ ptot, int n) {
    __shared__ int hist[NPB];
    __shared__ int red[NPB];
    int b = blockIdx.x;
    int lo = base[b], hi = base[b + 1];
    int t = threadIdx.x;
    if (t < NPB) hist[t] = 0;
    __syncthreads();
    for (int i = lo + t; i < hi; i += 512) atomicAdd(&hist[rec[i] >> 17], 1);
    __syncthreads();
    if (t < NPB) {
        int node = b * NPB + t;
        int dg = hist[t];  // nodes >= n never occur in rec -> dg == 0
        deg[node] = dg;
        dinv[node] = rsqrtf((float)dg + 1.0f);
        red[t] = (dg + 7) & ~7;
    }
    __syncthreads();
    for (int o = 64; o > 0; o >>= 1) {
        if (t < o) red[t] += red[t + o];
        __syncthreads();
    }
    if (t == 0) ptot[b] = red[0];
}

// Phase B: padded per-node segments; scatter edges; fill pad slots with zero-node (n)
__global__ __launch_bounds__(512) void bucket_csr_b(const unsigned int* __restrict__ rec,
                                                    const int* __restrict__ base,
                                                    const int* __restrict__ deg,
                                                    const int* __restrict__ pbase,
                                                    int* __restrict__ pbeg, int* __restrict__ pend,
                                                    int* __restrict__ cpad, int n) {
    __shared__ int sc[NPB];
    __shared__ int cur[NPB];
    int b = blockIdx.x;
    int lo = base[b], hi = base[b + 1];
    int t = threadIdx.x;
    int dg = 0, pdg = 0;
    if (t < NPB) {
        dg = deg[b * NPB + t];
        pdg = (dg + 7) & ~7;
        sc[t] = pdg;
    }
    __syncthreads();
    for (int off = 1; off < NPB; off <<= 1) {
        int a = (t < NPB && t >= off) ? sc[t - off] : 0;
        __syncthreads();
        if (t < NPB) sc[t] += a;
        __syncthreads();
    }
    int pos0 = 0;
    if (t < NPB) {
        pos0 = pbase[b] + sc[t] - pdg;
        int node = b * NPB + t;
        if (node < n) {
            pbeg[node] = pos0;
            pend[node] = pos0 + pdg;
        }
        cur[t] = pos0;
    }
    __syncthreads();
    for (int i = lo + t; i < hi; i += 512) {
        unsigned int r = rec[i];
        int pos = atomicAdd(&cur[r >> 17], 1);
        cpad[pos] = (int)(r & 0x1FFFFu);
    }
    // fill pad slots (disjoint from scattered region; no sync needed)
    if (t < NPB) {
        for (int p = pos0 + dg; p < pos0 + pdg; p++) cpad[p] = n;  // zero-node index
    }
}

// ---------------- x -> fp8 pre-scaled, SLICE-MAJOR: xp[slice][node][8 dwords] ----------------
__global__ void convert_x_pre(const float* __restrict__ x, const float* __restrict__ dinv,
                              unsigned int* __restrict__ xp, int n) {
    int tid = blockIdx.x * blockDim.x + threadIdx.x;  // over n*F_IN/4 dword groups
    if (tid >= n * (F_IN / 4)) return;
    int node = tid >> 5;  // F_IN/4 = 32 dwords per node
    int d = tid & 31;     // dword within node; slice = d>>3
    float di = dinv[node];
    float4 v = ((const float4*)x)[tid];
    xp[(size_t)(d >> 3) * ((size_t)(N_NODES + 1) * 8) + (size_t)node * 8 + (d & 7)] =
        pack4_fp8(v.x * di, v.y * di, v.z * di, v.w * di);
}

// ---------------- pack W[K][256] fp32 -> hi/lo bf16 in MFMA B-fragment order ----------------
__global__ void pack_w(const float* __restrict__ W, unsigned short* __restrict__ hi,
                       unsigned short* __restrict__ lo, int K) {
    int idx = blockIdx.x * blockDim.x + threadIdx.x;
    if (idx >= K * HDIM) return;
    int k = idx >> 8, c = idx & 255;
    float w = W[idx];
    unsigned short h = f2bf(w);
    float hf = __uint_as_float((unsigned int)h << 16);
    unsigned short l = f2bf(w - hf);
    int pos = ((k >> 5) * 16 + (c >> 4)) * 512 + ((((k >> 3) & 3) * 16) + (c & 15)) * 8 + (k & 7);
    hi[pos] = h;
    lo[pos] = l;
}

// ---------------- XCD-pinned feature-sliced aggregation, LDS-staged CSR ----------------
// Input h: fp8, slice-major [NS][N+1][32B] (row N = zeros). Output: bf16 [NS][N][32].
// Wave = 16 nodes x 4 lanes; lane (g,f) owns node g's feature-dwords 2f,2f+1 (8B gathers).
// The block's 128 nodes have CONTIGUOUS padded-csr segments -> the whole range is staged
// into LDS with coalesced 512-thread loads (the only csr HBM traffic, full-BW stream),
// then lanes walk their segments from LDS (few-cycle latency, 4-lane broadcast free).
// This removes the divergent scattered csr reads + their ~800cy exposed L2-miss latency
// that bounded R3/R5. Fallback to direct global walk if range > LDS_INTS (never expected).
// NS==8: slice = blockIdx&7 (one XCD per slice, 3.2MB L2-resident).
// NS==4: slice = (blockIdx&7)&3, node range split across the XCD pairs.
#define ACC4(v)                                             \
    a0 += __builtin_amdgcn_cvt_pk_f32_fp8((int)v.x, false); \
    a1 += __builtin_amdgcn_cvt_pk_f32_fp8((int)v.x, true);  \
    a2 += __builtin_amdgcn_cvt_pk_f32_fp8((int)v.y, false); \
    a3 += __builtin_amdgcn_cvt_pk_f32_fp8((int)v.y, true);

template <int NS>
__global__ __launch_bounds__(512, 4) void csr_agg_l(
    const unsigned char* __restrict__ h, const int* __restrict__ pbeg,
    const int* __restrict__ pend, const int* __restrict__ csr,
    const float* __restrict__ dinv, unsigned short* __restrict__ out, int n) {
    __shared__ int lbuf[LDS_INTS];
    int b7 = blockIdx.x & 7;
    int slice, node0;
    if (NS == 8) {
        slice = b7;
        node0 = (blockIdx.x >> 3) * 128;
    } else {
        slice = b7 & 3;
        node0 = (b7 >> 2) * (N_NODES / 2) + (blockIdx.x >> 3) * 128;
    }
    int tid = threadIdx.x;
    int lastn = node0 + 127;
    if (lastn >= n) lastn = n - 1;
    int rb = pbeg[node0];
    int re = pend[lastn];
    int range = re - rb;
    bool fits = range <= LDS_INTS;
    if (fits) {
        for (int i = tid; i < range; i += 512) lbuf[i] = csr[rb + i];
    }
    __syncthreads();

    int wave = tid >> 6, lane = tid & 63;
    int g = lane >> 2, f = lane & 3;
    int node = node0 + wave * 16 + g;
    if (node >= n) return;
    const unsigned char* hb = h + (size_t)slice * SIN;  // wave-uniform base
    unsigned int foff = (unsigned int)(f << 3);
    f32x2 a0 = {0.f, 0.f}, a1 = {0.f, 0.f}, a2 = {0.f, 0.f}, a3 = {0.f, 0.f};

    if (fits) {
        int pb = pbeg[node] - rb, pe = pend[node] - rb;
        for (int i = pb; i < pe; i += 8) {
            i32x4 sa = *(const i32x4*)(lbuf + i);
            i32x4 sb = *(const i32x4*)(lbuf + i + 4);
            uint2 v0 = *(const uint2*)(hb + (((unsigned int)sa.x << 5) + foff));
            uint2 v1 = *(const uint2*)(hb + (((unsigned int)sa.y << 5) + foff));
            uint2 v2 = *(const uint2*)(hb + (((unsigned int)sa.z << 5) + foff));
            uint2 v3 = *(const uint2*)(hb + (((unsigned int)sa.w << 5) + foff));
            uint2 v4 = *(const uint2*)(hb + (((unsigned int)sb.x << 5) + foff));
            uint2 v5 = *(const uint2*)(hb + (((unsigned int)sb.y << 5) + foff));
            uint2 v6 = *(const uint2*)(hb + (((unsigned int)sb.z << 5) + foff));
            uint2 v7 = *(const uint2*)(hb + (((unsigned int)sb.w << 5) + foff));
            ACC4(v0) ACC4(v1) ACC4(v2) ACC4(v3)
            ACC4(v4) ACC4(v5) ACC4(v6) ACC4(v7)
        }
    } else {  // safety fallback: direct global walk (never expected for this graph)
        int pb = pbeg[node], pe = pend[node];
        for (int i = pb; i < pe; i += 8) {
            i32x4 sa = *(const i32x4*)(csr + i);
            i32x4 sb = *(const i32x4*)(csr + i + 4);
            uint2 v0 = *(const uint2*)(hb + (((unsigned int)sa.x << 5) + foff));
            uint2 v1 = *(const uint2*)(hb + (((unsigned int)sa.y << 5) + foff));
            uint2 v2 = *(const uint2*)(hb + (((unsigned int)sa.z << 5) + foff));
            uint2 v3 = *(const uint2*)(hb + (((unsigned int)sa.w << 5) + foff));
            uint2 v4 = *(const uint2*)(hb + (((unsigned int)sb.x << 5) + foff));
            uint2 v5 = *(const uint2*)(hb + (((unsigned int)sb.y << 5) + foff));
            uint2 v6 = *(const uint2*)(hb + (((unsigned int)sb.z << 5) + foff));
            uint2 v7 = *(const uint2*)(hb + (((unsigned int)sb.w << 5) + foff));
            ACC4(v0) ACC4(v1) ACC4(v2) ACC4(v3)
            ACC4(v4) ACC4(v5) ACC4(v6) ACC4(v7)
        }
    }

    // self loop (pre-scaled by dinv at producer)
    uint2 sv = *(const uint2*)(hb + (((unsigned int)node << 5) + foff));
    ACC4(sv)
    float dn = dinv[node];
    u32x4 o;
    o.x = (unsigned int)f2bf(a0.x * dn) | ((unsigned int)f2bf(a0.y * dn) << 16);
    o.y = (unsigned int)f2bf(a1.x * dn) | ((unsigned int)f2bf(a1.y * dn) << 16);
    o.z = (unsigned int)f2bf(a2.x * dn) | ((unsigned int)f2bf(a2.y * dn) << 16);
    o.w = (unsigned int)f2bf(a3.x * dn) | ((unsigned int)f2bf(a3.y * dn) << 16);
    // 4 lanes x 16B = 64B contiguous per node-slice
    *(u32x4*)(out + (size_t)slice * ASE + (size_t)node * 32 + (f << 3)) = o;
}

// ---------------- MFMA GEMM: act(A[n,K] @ (Whi+Wlo) + b) ----------------
// A is SLICE-MAJOR bf16 [K/32][N][32]: k-tile kt == slice kt.
// block: 4 waves = 64 rows x 256 cols; wave: 32 rows (2 strips) x 128 cols (8 ct)
// MODE 0: out fp8 slice-major [8][N+1][32] = fp8(dinv[row]*relu(v))   (feeds agg<8>)
// MODE 2: out bf16 row-major [N][256] = bf16(relu(v))                 (feeds pooling)
template <int K, int MODE>
__global__ __launch_bounds__(256, 3) void gemm_mfma(
    const unsigned short* __restrict__ A, const unsigned short* __restrict__ Whi,
    const unsigned short* __restrict__ Wlo, const float* __restrict__ bias,
    const float* __restrict__ dinv, void* __restrict__ outp, int n) {
    int wave = threadIdx.x >> 6, lane = threadIdx.x & 63;
    int quad = lane >> 4, l16 = lane & 15;
    int rowgrp = wave >> 1, colhalf = wave & 1;
    int rowbase = blockIdx.x * 64 + rowgrp * 32;

    f32x4 acc[2][8];
#pragma unroll
    for (int s = 0; s < 2; s++)
#pragma unroll
        for (int ct = 0; ct < 8; ct++) acc[s][ct] = (f32x4){0.f, 0.f, 0.f, 0.f};

    int r0 = rowbase + l16;
    int r1 = rowbase + 16 + l16;
    int rc0 = r0 < n ? r0 : n - 1;
    int rc1 = r1 < n ? r1 : n - 1;

    for (int kt = 0; kt < K / 32; kt++) {
        bf16x8 a0 = *(const bf16x8*)(A + (size_t)kt * ASE + (size_t)rc0 * 32 + quad * 8);
        bf16x8 a1 = *(const bf16x8*)(A + (size_t)kt * ASE + (size_t)rc1 * 32 + quad * 8);
        const unsigned short* wh = Whi + ((size_t)kt * 16 + colhalf * 8) * 512 + lane * 8;
        const unsigned short* wl = Wlo + ((size_t)kt * 16 + colhalf * 8) * 512 + lane * 8;
#pragma unroll
        for (int ct = 0; ct < 8; ct++) {
            bf16x8 bh = *(const bf16x8*)(wh + ct * 512);
            bf16x8 bl = *(const bf16x8*)(wl + ct * 512);
            acc[0][ct] = __builtin_amdgcn_mfma_f32_16x16x32_bf16(a0, bh, acc[0][ct], 0, 0, 0);
            acc[0][ct] = __builtin_amdgcn_mfma_f32_16x16x32_bf16(a0, bl, acc[0][ct], 0, 0, 0);
            acc[1][ct] = __builtin_amdgcn_mfma_f32_16x16x32_bf16(a1, bh, acc[1][ct], 0, 0, 0);
            acc[1][ct] = __builtin_amdgcn_mfma_f32_16x16x32_bf16(a1, bl, acc[1][ct], 0, 0, 0);
        }
    }

#pragma unroll
    for (int s = 0; s < 2; s++) {
#pragma unroll
        for (int ct = 0; ct < 8; ct++) {
            int col = colhalf * 128 + ct * 16 + l16;
            float b = bias[col];
#pragma unroll
            for (int r = 0; r < 4; r++) {
                int row = rowbase + s * 16 + quad * 4 + r;
                if (row < n) {
                    float v = acc[s][ct][r] + b;
                    v = v > 0.0f ? v : 0.0f;
                    if (MODE == 0) {
                        ((unsigned char*)outp)[(size_t)(col >> 5) * SIN + (size_t)row * 32 +
                                               (col & 31)] = pack1_fp8(v * dinv[row]);
                    } else {
                        ((unsigned short*)outp)[(size_t)row * HDIM + col] = f2bf(v);
                    }
                }
            }
        }
    }
}

// ---------------- pooling (batch sorted -> run-length), bf16 input ----------------
__global__ void pool_sum_runs(const unsigned short* __restrict__ h, const int* __restrict__ batch,
                              float* __restrict__ pool, int n) {
    constexpr int ROWS = 128;
    int f = threadIdx.x;
    int r0 = blockIdx.x * ROWS;
    int rend = r0 + ROWS;
    if (rend > n) rend = n;
    float acc = 0.0f;
    int cur = batch[r0];
    for (int r = r0; r < rend; r++) {
        int g = batch[r];
        if (g != cur) {
            atomicAdd(&pool[cur * HDIM + f], acc);
            acc = 0.0f; cur = g;
        }
        acc += bf2f(h[(size_t)r * HDIM + f]);
    }
    atomicAdd(&pool[cur * HDIM + f], acc);
}

// ---------------- head: mean (cnt via binary search on sorted batch) + FC + log_softmax ----
__global__ void final_head(const float* __restrict__ pool, const int* __restrict__ batch,
                           const float* __restrict__ fcw, const float* __restrict__ fcb,
                           float* __restrict__ out, int n) {
    int g = threadIdx.x;
    if (g < N_GRAPHS) {
        int lo = 0, hi = n;
        while (lo < hi) { int m = (lo + hi) >> 1; if (batch[m] < g) lo = m + 1; else hi = m; }
        int b0 = lo;
        lo = 0; hi = n;
        while (lo < hi) { int m = (lo + hi) >> 1; if (batch[m] < g + 1) lo = m + 1; else hi = m; }
        int c = lo - b0;
        float cf = c > 1 ? (float)c : 1.0f;
        float inv = 1.0f / cf;
        float l0 = fcb[0], l1 = fcb[1];
        for (int f = 0; f < HDIM; f++) {
            float p = pool[g * HDIM + f] * inv;
            l0 += p * fcw[f * 2 + 0];
            l1 += p * fcw[f * 2 + 1];
        }
        float m = fmaxf(l0, l1);
        float lse = m + logf(expf(l0 - m) + expf(l1 - m));
        out[g * 2 + 0] = l0 - lse;
        out[g * 2 + 1] = l1 - lse;
    }
}

extern "C" void kernel_launch(void* const* d_in, const int* in_sizes, int n_in,
                              void* d_out, int out_size, void* d_ws, size_t ws_size,
                              hipStream_t stream) {
    const float* x = (const float*)d_in[0];
    const int* ei = (const int*)d_in[1];
    const int* batch = (const int*)d_in[2];
    const float* W1 = (const float*)d_in[3];
    const float* b1 = (const float*)d_in[4];
    const float* W2 = (const float*)d_in[5];
    const float* b2 = (const float*)d_in[6];
    const float* fcw = (const float*)d_in[7];
    const float* fcb = (const float*)d_in[8];
    float* out = (float*)d_out;

    const int* src = ei;
    const int* dst = ei + N_EDGES;

    // ---- workspace layout (bytes) ----
    char* ws = (char*)d_ws;
    float* dinv = (float*)ws;            ws += 4 * (size_t)NODE_PAD;
    int* deg = (int*)ws;                 ws += 4 * (size_t)NODE_PAD;
    int* pbeg = (int*)ws;                ws += 4 * (size_t)NODE_PAD;
    int* pend = (int*)ws;                ws += 4 * (size_t)NODE_PAD;
    int* csr_pad = (int*)ws;             ws += 4 * ((size_t)N_EDGES + 7 * N_NODES + 64);
    int* counts = (int*)ws;              ws += 4 * (size_t)NCHUNK * N_BUCKETS;
    int* offs = (int*)ws;                ws += 4 * (size_t)NCHUNK * N_BUCKETS;
    int* tot = (int*)ws;                 ws += 4 * 1024;
    int* bbase = (int*)ws;               ws += 4 * 1024;
    int* ptot = (int*)ws;                ws += 4 * 1024;
    int* pbase = (int*)ws;               ws += 4 * 1024;
    unsigned short* W1hi = (unsigned short*)ws; ws += 2 * F_IN * HDIM;
    unsigned short* W1lo = (unsigned short*)ws; ws += 2 * F_IN * HDIM;
    unsigned short* W2hi = (unsigned short*)ws; ws += 2 * HDIM * HDIM;
    unsigned short* W2lo = (unsigned short*)ws; ws += 2 * HDIM * HDIM;
    float* pool = (float*)ws;            ws += 4 * N_GRAPHS * HDIM;
    // R0 region (102.4MB): x_pre fp8 [4][N+1][32] | A1 bf16 [4][N][32] | h1_pre fp8 [8][N+1][32]
    // h2 [N][256] bf16 overlays R0 start (x_pre/A1/h1_pre dead by gemm2)
    char* R0 = ws;                       ws += 4 * (size_t)N_NODES * HDIM;
    unsigned char* x_pre = (unsigned char*)R0;
    unsigned short* A1 = (unsigned short*)(R0 + 12800256);          // 4*SIN=12800128, aligned 256
    unsigned char* h1_pre = (unsigned char*)(R0 + 12800256 + 2 * 4 * ASE);  // +25.6MB
    unsigned short* h2 = (unsigned short*)R0;
    unsigned short* A2 = (unsigned short*)ws;  // [8][N][32] bf16 (layer 2 only), 51.2MB
    // records overlay A2 (dead until layer 2): N_EDGES*4 = 12.8MB <= 51.2MB
    unsigned int* records = (unsigned int*)A2;

    // ---- atomic-free bucketed padded-CSR build + dinv ----
    block_count<<<NCHUNK, 256, 0, stream>>>(dst, counts, N_EDGES);
    bucket_totals<<<N_BUCKETS, 256, 0, stream>>>(counts, tot);
    scan_buckets<<<1, 1024, 0, stream>>>(tot, bbase, N_BUCKETS);
    column_scan<<<N_BUCKETS, 512, 0, stream>>>(counts, bbase, offs);
    block_scatter<<<NCHUNK, 256, 0, stream>>>(src, dst, offs, records, N_EDGES);
    bucket_csr_a<<<N_BUCKETS, 512, 0, stream>>>(records, bbase, deg, dinv, ptot, N_NODES);
    scan_buckets<<<1, 1024, 0, stream>>>(ptot, pbase, N_BUCKETS);
    bucket_csr_b<<<N_BUCKETS, 512, 0, stream>>>(records, bbase, deg, pbase, pbeg, pend,
                                                csr_pad, N_NODES);

    // ---- conversions / weight packing / zero inits ----
    zero_rows<<<1, 128, 0, stream>>>((unsigned int*)x_pre, (unsigned int*)h1_pre);
    convert_x_pre<<<(N_NODES * (F_IN / 4) + 255) / 256, 256, 0, stream>>>(
        x, dinv, (unsigned int*)x_pre, N_NODES);
    pack_w<<<(F_IN * HDIM + 255) / 256, 256, 0, stream>>>(W1, W1hi, W1lo, F_IN);
    pack_w<<<(HDIM * HDIM + 255) / 256, 256, 0, stream>>>(W2, W2hi, W2lo, HDIM);
    zero_f<<<(N_GRAPHS * HDIM + 255) / 256, 256, 0, stream>>>(pool, N_GRAPHS * HDIM);

    // ---- layer 1: 4 slices, node range split across XCD pairs ----
    csr_agg_l<4><<<((N_NODES / 2 + 127) / 128) * 8, 512, 0, stream>>>(
        x_pre, pbeg, pend, csr_pad, dinv, A1, N_NODES);
    gemm_mfma<F_IN, 0><<<(N_NODES + 63) / 64, 256, 0, stream>>>(A1, W1hi, W1lo, b1, dinv,
                                                                h1_pre, N_NODES);
    // ---- layer 2: 8 slices, one XCD per slice ----
    csr_agg_l<8><<<((N_NODES + 127) / 128) * 8, 512, 0, stream>>>(
        h1_pre, pbeg, pend, csr_pad, dinv, A2, N_NODES);
    gemm_mfma<HDIM, 2><<<(N_NODES + 63) / 64, 256, 0, stream>>>(A2, W2hi, W2lo, b2, dinv,
                                                                h2, N_NODES);

    // ---- pool + head ----
    pool_sum_runs<<<(N_NODES + 127) / 128, 256, 0, stream>>>(h2, batch, pool, N_NODES);
    final_head<<<1, 64, 0, stream>>>(pool, batch, fcw, fcb, out, N_NODES);
}